// Round 9
// baseline (709.167 us; speedup 1.0000x reference)
//
#include <hip/hip_runtime.h>
#include <hip/hip_bf16.h>

// ---------------------------------------------------------------------------
// Quantum ViT: B=128, T=127, D_IN=48, DK=S=128, H=8, L=6, P=8128
// Inputs: all float32. Output: float32 [B, DK]. bf16 MFMA internals.
//
// R9: structural de-launch. merge kernel eliminated — attn sums the previous
// layer's 8 hs slices during staging (same f32 sum order => bit-identical h),
// computes row norms inline (16-lane shfl groups), re-sums the residual in the
// epilogue. hs ping-pongs (2 buffers). embed reworked: 4 tokens/block so ew is
// read once per block (L2 traffic 400->100 MB). sincos+vw_frag fused.
// Launches: prep, build_w, embed, 6x attn, finalize = 10 (was 16).
// ---------------------------------------------------------------------------

typedef __bf16 bf16x8 __attribute__((ext_vector_type(8)));
typedef float  f32x4  __attribute__((ext_vector_type(4)));
typedef unsigned int u32;

// swizzled LDS index for a 128x128 bf16 tile: chunk(col/8) ^= row&15.
__device__ __forceinline__ int sidx(int row, int col)
{
    return row * 128 + ((((col >> 3) ^ (row & 15)) << 3) | (col & 7));
}

// ---------------------------------------------------------------------------
// 0) prep: [blocks 0..3071] sincos table (layer-major, 256 layers, pad=identity)
//          [blocks 3072..3455] Vw f32 -> bf16 fragment-major
// ---------------------------------------------------------------------------
__global__ void __launch_bounds__(256)
prep_kernel(const float* __restrict__ phi, float2* __restrict__ csn,
            const float* __restrict__ vw,  __bf16* __restrict__ cvwf)
{
    if (blockIdx.x < 3072) {
        const int mat = blockIdx.x >> 6;
        const int t   = ((blockIdx.x & 63) << 2) + (threadIdx.x >> 6);
        const int j   = threadIdx.x & 63;
        float th = 0.f;
        if (t < 253) {
            const int p = t & 1, i = 2 * j + p;
            const int lim = min(t, 252 - t);
            if (i <= lim) {
                const int k = (t + i) >> 1;
                th = phi[mat * 8128 + ((k * (k + 1)) >> 1) + (k - i)];
            }
        }
        float sn, cs;
        __sincosf(th, &sn, &cs);
        csn[(mat * 256 + t) * 64 + j] = make_float2(cs, sn);
    } else {
        const int f    = (blockIdx.x - 3072) * 256 + threadIdx.x;  // 98304 frags
        const int lane = f & 63;
        const int k0   = (f >> 6) & 3;
        const int t    = (f >> 8) & 7;
        const int lh   = f >> 11;
        const int row  = t * 16 + (lane & 15);
        const int col  = k0 * 32 + (lane >> 4) * 8;
        const float* src = vw + (lh * 128 + row) * 128 + col;
        __bf16* dst = cvwf + f * 8;
#pragma unroll
        for (int j = 0; j < 8; j++) dst[j] = (__bf16)src[j];
    }
}

// ---------------------------------------------------------------------------
// 1) W build: 253 parallel Givens layers (time(k,i)=2k-i), 16-layer groups,
//    3-slot register buffer, prefetch 2 groups ahead. 4 cols/block.
//    Output Wt[mat][c][d] = W[d][c] (bf16, B-operand layout).
// ---------------------------------------------------------------------------
__global__ void __launch_bounds__(64)
build_w_kernel(const float2* __restrict__ csn, __bf16* __restrict__ wt)
{
    const int mat = blockIdx.x >> 5;
    const int grp = blockIdx.x & 31;
    const int c0  = grp * 4;
    const int lam = threadIdx.x;

    const float2* base = csn + (mat * 256) * 64 + lam;

    float vlo[4], vhi[4];
#pragma unroll
    for (int j = 0; j < 4; j++) {
        vlo[j] = (2 * lam     == c0 + j) ? 1.f : 0.f;
        vhi[j] = (2 * lam + 1 == c0 + j) ? 1.f : 0.f;
    }

    float2 buf[3][16];
#pragma unroll
    for (int k = 0; k < 16; k++) buf[0][k] = base[k * 64];
#pragma unroll
    for (int k = 0; k < 16; k++) buf[1][k] = base[(16 + k) * 64];

#pragma unroll
    for (int g = 0; g < 16; g++) {
        const int cb = g % 3;
        if (g < 14) {
            const int nb = (g + 2) % 3;
#pragma unroll
            for (int k = 0; k < 16; k++)
                buf[nb][k] = base[((g + 2) * 16 + k) * 64];
        }
#pragma unroll
        for (int p = 0; p < 8; p++) {
            {
                const float cs = buf[cb][2 * p].x, sn = buf[cb][2 * p].y;
#pragma unroll
                for (int j = 0; j < 4; j++) {
                    float lo = vlo[j], hi = vhi[j];
                    vlo[j] = cs * lo - sn * hi;
                    vhi[j] = sn * lo + cs * hi;
                }
            }
            {
                const float cs = buf[cb][2 * p + 1].x, sn = buf[cb][2 * p + 1].y;
#pragma unroll
                for (int j = 0; j < 4; j++) {
                    float y  = __shfl_down(vlo[j], 1);
                    float x  = vhi[j];
                    float xn = cs * x - sn * y;
                    float yn = sn * x + cs * y;
                    vhi[j] = xn;
                    float z = __shfl_up(yn, 1);
                    if (lam > 0) vlo[j] = z;
                }
            }
        }
    }

    u32* wtu = (u32*)wt;
#pragma unroll
    for (int j = 0; j < 4; j++) {
        __bf16 va = (__bf16)vlo[j];
        __bf16 vb = (__bf16)vhi[j];
        u32 pk = (u32)__builtin_bit_cast(unsigned short, va)
               | ((u32)__builtin_bit_cast(unsigned short, vb) << 16);
        wtu[mat * 8192 + (c0 + j) * 64 + lam] = pk;
    }
}

// ---------------------------------------------------------------------------
// 2) embed: 512 thr = 4 tokens/block (ew read once per block via L1).
//    grid = grp*128 + b (32 grps of 4 tokens). LN0 -> hf (f32), hb (bf16).
// ---------------------------------------------------------------------------
__global__ void __launch_bounds__(512)
embed_kernel(const float* __restrict__ x,  const float* __restrict__ ew,
             const float* __restrict__ eb, const float* __restrict__ ct,
             const float* __restrict__ g0, const float* __restrict__ b0,
             float* __restrict__ hf, __bf16* __restrict__ hb)
{
    __shared__ float sx[4][48];
    __shared__ float sred[4][2];
    const int d  = threadIdx.x & 127, sq = threadIdx.x >> 7;
    const int wh = (threadIdx.x >> 6) & 1;           // which wave of subgroup
    const int b  = blockIdx.x & 127;
    const int s  = (blockIdx.x >> 7) * 4 + sq;

    if (s > 0 && d < 48) sx[sq][d] = x[(b * 127 + (s - 1)) * 48 + d];
    __syncthreads();

    float val;
    if (s == 0) {
        val = ct[d];
    } else {
        float aa = 0.f;
#pragma unroll
        for (int f = 0; f < 48; f++) aa = fmaf(sx[sq][f], ew[d * 48 + f], aa);
        val = aa + eb[d];
    }
    // mean over the 128-thread subgroup
    float v = val;
#pragma unroll
    for (int m = 32; m; m >>= 1) v += __shfl_xor(v, m);
    if ((threadIdx.x & 63) == 0) sred[sq][wh] = v;
    __syncthreads();
    float mean = (sred[sq][0] + sred[sq][1]) * (1.f / 128.f);
    float xc   = val - mean;
    __syncthreads();                                  // sred reuse
    v = xc * xc;
#pragma unroll
    for (int m = 32; m; m >>= 1) v += __shfl_xor(v, m);
    if ((threadIdx.x & 63) == 0) sred[sq][wh] = v;
    __syncthreads();
    float var = (sred[sq][0] + sred[sq][1]) * (1.f / 128.f);
    float y   = xc * rsqrtf(var + 1e-5f) * g0[d] + b0[d];

    const int o = (b * 128 + s) * 128 + d;
    hf[o] = y;
    hb[o] = (__bf16)y;
}

// ---------------------------------------------------------------------------
// 3) fused attention head + inline head-merge of the PREVIOUS layer.
//    One WG per (head, batch), 512 thr = 8 waves, wave owns 16 rows.
//    Staging (l>0): h = mb[l-1] + sum_h hs_prev  (same f32 order as old merge)
//    Row norms Sum(h^2) computed inline via 16-lane shfl groups -> sInvR.
//    A: T1 = h @ W | B: G = T1 @ h^T, softmax -> Pm | C: V = h @ Vw^T
//    D: O = Pm @ V, + residual (re-summed from hs_prev), LN, *mw -> hs.
// ---------------------------------------------------------------------------
__global__ void __launch_bounds__(512, 4)
attn_kernel(int l, int first,
            const float*  __restrict__ hf,   const __bf16* __restrict__ hsrc,
            const __bf16* __restrict__ wt,   const __bf16* __restrict__ vwf,
            const float*  __restrict__ vb,   const float* __restrict__ lng,
            const float*  __restrict__ lnb,  const float* __restrict__ mwp,
            const float*  __restrict__ mbp,  __bf16* __restrict__ hs)
{
    __shared__ __align__(16) __bf16 sH[128 * 128];
    __shared__ __align__(16) __bf16 sY[128 * 128];
    __shared__ float sInvR[128];   // Sum h^2 per row
    __shared__ float sVb[128];
    __shared__ float sLg[128];
    __shared__ float sLb[128];

    const int tid  = threadIdx.x;
    const int lane = tid & 63, w = tid >> 6;
    const int l15  = lane & 15, quad = lane >> 4;
    const int b    = blockIdx.x & 127;   // XCD = b%8
    const int hh   = blockIdx.x >> 7;
    const int lh   = l * 8 + hh;

    const __bf16* wtp = wt + lh * 16384;
    const float mbv = first ? 0.f : mbp[l - 1];

    // ---- stage sH (h, summed from hs_prev for l>0) + sY (Wt), swizzled ----
#pragma unroll
    for (int c = 0; c < 4; c++) {
        int ch  = tid + c * 512;          // 2048 chunks of 8 bf16
        int row = ch >> 4, cc = ch & 15;
        bf16x8 wv = *(const bf16x8*)(wtp + ch * 8);
        float v[8];
        if (first) {
            bf16x8 hv = *(const bf16x8*)(hsrc + b * 16384 + ch * 8);
#pragma unroll
            for (int j = 0; j < 8; j++) v[j] = (float)hv[j];
        } else {
#pragma unroll
            for (int j = 0; j < 8; j++) v[j] = mbv;
#pragma unroll
            for (int h8 = 0; h8 < 8; h8++) {
                bf16x8 tv = *(const bf16x8*)(hsrc + (size_t)h8 * 2097152
                                             + (b * 128 + row) * 128 + cc * 8);
#pragma unroll
                for (int j = 0; j < 8; j++) v[j] += (float)tv[j];
            }
        }
        float ss = 0.f;
        bf16x8 hv8;
#pragma unroll
        for (int j = 0; j < 8; j++) { ss = fmaf(v[j], v[j], ss); hv8[j] = (__bf16)v[j]; }
        *(bf16x8*)(&sH[sidx(row, cc * 8)]) = hv8;
        *(bf16x8*)(&sY[sidx(row, cc * 8)]) = wv;
        // 16 consecutive tids share a row -> reduce within the group
#pragma unroll
        for (int m = 1; m < 16; m <<= 1) ss += __shfl_xor(ss, m);
        if ((tid & 15) == 0) sInvR[row] = ss;
    }
    if (tid < 128) {
        sVb[tid] = vb[lh * 128 + tid];
        sLg[tid] = lng[lh * 128 + tid];
        sLb[tid] = lnb[lh * 128 + tid];
    }
    __syncthreads();  // B1

    const int r0 = w * 16;
    const int kq = quad * 8;
    const int q4 = quad * 4;
    const f32x4 vzero = {0.f, 0.f, 0.f, 0.f};

    f32x4 acc[8];

    auto mmL = [&](const __bf16* Ab, const __bf16* Bb) {
#pragma unroll
        for (int t = 0; t < 8; t++) acc[t] = vzero;
#pragma unroll
        for (int k0 = 0; k0 < 128; k0 += 32) {
            const int kk = k0 + kq;
            bf16x8 a0 = *(const bf16x8*)(&Ab[sidx(r0 + l15, kk)]);
#pragma unroll
            for (int t = 0; t < 8; t++) {
                bf16x8 bb = *(const bf16x8*)(&Bb[sidx(t * 16 + l15, kk)]);
                acc[t] = __builtin_amdgcn_mfma_f32_16x16x32_bf16(a0, bb, acc[t], 0, 0, 0);
            }
        }
    };

    // ================= Phase A: T1 = h @ W =================
    mmL(sH, sY);
    __syncthreads();  // B2: all waves done reading sY(Wt)
#pragma unroll
    for (int t = 0; t < 8; t++)
#pragma unroll
        for (int r = 0; r < 4; r++)
            sY[sidx(r0 + q4 + r, t * 16 + l15)] = (__bf16)acc[t][r];
    // no barrier: phase B reads only this wave's own T1 rows

    // ================= Phase B: G = T1 @ h^T =================
    mmL(sY, sH);

    // ---- softmax (base 2): v = G^2*inv_s*inv_t*(scale*log2e) -> Pm in sY ---
    {
        const float scale2 = 0.08838834764831843f * 1.4426950408889634f;
        float invt[8];
#pragma unroll
        for (int t = 0; t < 8; t++) invt[t] = rsqrtf(sInvR[t * 16 + l15]);
        float invs[4];
#pragma unroll
        for (int r = 0; r < 4; r++) invs[r] = rsqrtf(sInvR[r0 + q4 + r]);

        float mx[4] = {-3e38f, -3e38f, -3e38f, -3e38f};
#pragma unroll
        for (int t = 0; t < 8; t++)
#pragma unroll
            for (int r = 0; r < 4; r++) {
                float g = acc[t][r];
                float v = g * g * invs[r] * invt[t] * scale2;
                acc[t][r] = v;
                mx[r] = fmaxf(mx[r], v);
            }
#pragma unroll
        for (int m = 1; m < 16; m <<= 1)
#pragma unroll
            for (int r = 0; r < 4; r++) mx[r] = fmaxf(mx[r], __shfl_xor(mx[r], m));

        float sm[4] = {0.f, 0.f, 0.f, 0.f};
#pragma unroll
        for (int t = 0; t < 8; t++)
#pragma unroll
            for (int r = 0; r < 4; r++) {
                float e = exp2f(acc[t][r] - mx[r]);
                acc[t][r] = e;
                sm[r] += e;
            }
#pragma unroll
        for (int m = 1; m < 16; m <<= 1)
#pragma unroll
            for (int r = 0; r < 4; r++) sm[r] += __shfl_xor(sm[r], m);
#pragma unroll
        for (int r = 0; r < 4; r++) sm[r] = 1.0f / sm[r];
#pragma unroll
        for (int t = 0; t < 8; t++)
#pragma unroll
            for (int r = 0; r < 4; r++)
                sY[sidx(r0 + q4 + r, t * 16 + l15)] = (__bf16)(acc[t][r] * sm[r]);
    }

    // residual (consumed in epilogue): l=0 from hf; l>0 re-sum hs_prev (f32)
    float hres[8][4];
    if (first) {
        const float* hfp = hf + (b * 128 + r0 + q4) * 128;
#pragma unroll
        for (int t = 0; t < 8; t++)
#pragma unroll
            for (int r = 0; r < 4; r++)
                hres[t][r] = hfp[r * 128 + t * 16 + l15];
    } else {
#pragma unroll
        for (int r = 0; r < 4; r++) {
            const __bf16* hp = hsrc + (size_t)(b * 128 + r0 + q4 + r) * 128;
#pragma unroll
            for (int t = 0; t < 8; t++) {
                float s = mbv;
#pragma unroll
                for (int h8 = 0; h8 < 8; h8++)
                    s += (float)hp[(size_t)h8 * 2097152 + t * 16 + l15];
                hres[t][r] = s;
            }
        }
    }

    // ================= Phase C: V = h @ Vw^T (B-frags from global) ========
    {
        const __bf16* vbase = vwf + (size_t)lh * 16384;
#pragma unroll
        for (int t = 0; t < 8; t++) acc[t] = vzero;
#pragma unroll
        for (int k0c = 0; k0c < 4; k0c++) {
            const int kk = k0c * 32 + kq;
            bf16x8 a0 = *(const bf16x8*)(&sH[sidx(r0 + l15, kk)]);
#pragma unroll
            for (int t = 0; t < 8; t++) {
                bf16x8 bb = *(const bf16x8*)(vbase + ((t * 4 + k0c) * 64 + lane) * 8);
                acc[t] = __builtin_amdgcn_mfma_f32_16x16x32_bf16(a0, bb, acc[t], 0, 0, 0);
            }
        }
    }
    __syncthreads();  // B4: all waves done reading sH (phases B & C)

    {   // V^T into sH: sH[e][token]
        float vbv[8];
#pragma unroll
        for (int t = 0; t < 8; t++) vbv[t] = sVb[t * 16 + l15];
#pragma unroll
        for (int t = 0; t < 8; t++)
#pragma unroll
            for (int r = 0; r < 4; r++)
                sH[sidx(t * 16 + l15, r0 + q4 + r)] = (__bf16)(acc[t][r] + vbv[t]);
    }
    __syncthreads();  // B5

    // ================= Phase D: O = Pm @ V =================
    mmL(sY, sH);

    {   // epilogue: + residual, LN over d, *merger_w -> hs
        const float mw = mwp[lh];
        float lgv[8], lbv[8];
#pragma unroll
        for (int t = 0; t < 8; t++) {
            lgv[t] = sLg[t * 16 + l15];
            lbv[t] = sLb[t * 16 + l15];
        }
        float sum_[4] = {0.f, 0.f, 0.f, 0.f};
        float sq_[4]  = {0.f, 0.f, 0.f, 0.f};
#pragma unroll
        for (int t = 0; t < 8; t++)
#pragma unroll
            for (int r = 0; r < 4; r++) {
                float xx = acc[t][r] + hres[t][r];
                acc[t][r] = xx;
                sum_[r] += xx;
                sq_[r]  += xx * xx;
            }
#pragma unroll
        for (int m = 1; m < 16; m <<= 1)
#pragma unroll
            for (int r = 0; r < 4; r++) {
                sum_[r] += __shfl_xor(sum_[r], m);
                sq_[r]  += __shfl_xor(sq_[r], m);
            }
        float mean[4], rstd[4];
#pragma unroll
        for (int r = 0; r < 4; r++) {
            mean[r] = sum_[r] * (1.f / 128.f);
            float var = sq_[r] * (1.f / 128.f) - mean[r] * mean[r];
            rstd[r] = rsqrtf(fmaxf(var, 0.f) + 1e-5f);
        }
        __bf16* hsp = hs + ((hh * 128 + b) * 128 + r0 + q4) * 128;
#pragma unroll
        for (int t = 0; t < 8; t++)
#pragma unroll
            for (int r = 0; r < 4; r++) {
                float y = (acc[t][r] - mean[r]) * rstd[r] * lgv[t] + lbv[t];
                hsp[r * 128 + t * 16 + l15] = (__bf16)(y * mw);
            }
    }
}

// ---------------------------------------------------------------------------
// 4) finalize: out[b,:] = mb[5] + sum_h hs5[h,b,127,:]  (f32)
// ---------------------------------------------------------------------------
__global__ void __launch_bounds__(128)
finalize_kernel(const __bf16* __restrict__ hs5, const float* __restrict__ mbp,
                float* __restrict__ out)
{
    const int b = blockIdx.x, d = threadIdx.x;
    float acc = mbp[5];
#pragma unroll
    for (int h8 = 0; h8 < 8; h8++)
        acc += (float)hs5[(size_t)h8 * 2097152 + (b * 128 + 127) * 128 + d];
    out[b * 128 + d] = acc;
}

// ---------------------------------------------------------------------------
extern "C" void kernel_launch(void* const* d_in, const int* in_sizes, int n_in,
                              void* d_out, int out_size, void* d_ws, size_t ws_size,
                              hipStream_t stream)
{
    (void)in_sizes; (void)n_in; (void)out_size; (void)ws_size;

    const float* x   = (const float*)d_in[0];
    const float* ew  = (const float*)d_in[1];
    const float* eb  = (const float*)d_in[2];
    const float* ct  = (const float*)d_in[3];
    const float* g0  = (const float*)d_in[4];
    const float* b0  = (const float*)d_in[5];
    const float* vw  = (const float*)d_in[6];
    const float* vb  = (const float*)d_in[7];
    const float* lng = (const float*)d_in[8];
    const float* lnb = (const float*)d_in[9];
    const float* phi = (const float*)d_in[10];
    const float* mw  = (const float*)d_in[11];
    const float* mb  = (const float*)d_in[12];
    float* out = (float*)d_out;

    char* ws = (char*)d_ws;
    __bf16* wt   = (__bf16*)(ws);                 //  1,572,864
    float*  hf   = (float*)(ws + 1572864);        //  8,388,608
    __bf16* hb   = (__bf16*)(ws + 9961472);       //  4,194,304
    __bf16* hs0  = (__bf16*)(ws + 14155776);      // 33,554,432
    __bf16* hs1  = (__bf16*)(ws + 47710208);      // 33,554,432
    __bf16* cvwf = (__bf16*)(ws + 81264640);      //  1,572,864
    float2* csn  = (float2*)(ws + 82837504);      //  6,291,456  (~89.1 MB)

    prep_kernel<<<3456, 256, 0, stream>>>(phi, csn, vw, cvwf);
    build_w_kernel<<<1536, 64, 0, stream>>>(csn, wt);
    embed_kernel<<<4096, 512, 0, stream>>>(x, ew, eb, ct, g0, b0, hf, hb);

    __bf16* hsbuf[2] = {hs0, hs1};
    for (int l = 0; l < 6; l++) {
        const int first = (l == 0);
        const __bf16* hsrc = first ? hb : hsbuf[(l & 1) ^ 1];
        attn_kernel<<<1024, 512, 0, stream>>>(l, first, hf, hsrc, wt, cvwf,
                                              vb, lng, lnb, mw, mb, hsbuf[l & 1]);
    }
    finalize_kernel<<<128, 128, 0, stream>>>(hsbuf[1], mb, out);
}

// Round 10
// 463.362 us; speedup vs baseline: 1.5305x; 1.5305x over previous
//
#include <hip/hip_runtime.h>
#include <hip/hip_bf16.h>

// ---------------------------------------------------------------------------
// Quantum ViT: B=128, T=127, D_IN=48, DK=S=128, H=8, L=6, P=8128
// Inputs: all float32. Output: float32 [B, DK]. bf16 MFMA internals.
//
// R10: revert R9's inline merge (FETCH 154 MB, 709 us). Back to R8 structure
// (attn + merge). attn v5: BOTH weight operands (Wt and Vw) read from global
// in fragment-major layout (L1/L2-hot, immediate-offset loads) -> LDS traffic
// -45%, B-address VALU ~0, one barrier fewer. build_w emits wtf frag-major.
// Keep: prep fusion, 4-token embed (with invn), XOR swizzle, b-major grid.
// ---------------------------------------------------------------------------

typedef __bf16 bf16x8 __attribute__((ext_vector_type(8)));
typedef float  f32x4  __attribute__((ext_vector_type(4)));
typedef unsigned int u32;

// swizzled LDS index for a 128x128 bf16 tile: chunk(col/8) ^= row&15.
__device__ __forceinline__ int sidx(int row, int col)
{
    return row * 128 + ((((col >> 3) ^ (row & 15)) << 3) | (col & 7));
}

// ---------------------------------------------------------------------------
// 0) prep: [blocks 0..3071] sincos table (layer-major, 256 layers, pad=ident)
//          [blocks 3072..3455] Vw f32 -> bf16 fragment-major:
//          cvwf[((lh*8+t)*4+k0)*64+lane][j] = Vw[lh][t*16+(lane&15)]
//                                               [k0*32+(lane>>4)*8+j]
// ---------------------------------------------------------------------------
__global__ void __launch_bounds__(256)
prep_kernel(const float* __restrict__ phi, float2* __restrict__ csn,
            const float* __restrict__ vw,  __bf16* __restrict__ cvwf)
{
    if (blockIdx.x < 3072) {
        const int mat = blockIdx.x >> 6;
        const int t   = ((blockIdx.x & 63) << 2) + (threadIdx.x >> 6);
        const int j   = threadIdx.x & 63;
        float th = 0.f;
        if (t < 253) {
            const int p = t & 1, i = 2 * j + p;
            const int lim = min(t, 252 - t);
            if (i <= lim) {
                const int k = (t + i) >> 1;
                th = phi[mat * 8128 + ((k * (k + 1)) >> 1) + (k - i)];
            }
        }
        float sn, cs;
        __sincosf(th, &sn, &cs);
        csn[(mat * 256 + t) * 64 + j] = make_float2(cs, sn);
    } else {
        const int f    = (blockIdx.x - 3072) * 256 + threadIdx.x;  // 98304 frags
        const int lane = f & 63;
        const int k0   = (f >> 6) & 3;
        const int t    = (f >> 8) & 7;
        const int lh   = f >> 11;
        const int row  = t * 16 + (lane & 15);
        const int col  = k0 * 32 + (lane >> 4) * 8;
        const float* src = vw + (lh * 128 + row) * 128 + col;
        __bf16* dst = cvwf + f * 8;
#pragma unroll
        for (int j = 0; j < 8; j++) dst[j] = (__bf16)src[j];
    }
}

// ---------------------------------------------------------------------------
// 1) W build: 253 parallel Givens layers (time(k,i)=2k-i), 16-layer groups,
//    3-slot register buffer, prefetch 2 groups ahead. 4 cols/block.
//    Output wtf FRAGMENT-MAJOR (B-operand frags for T1 = h @ W):
//    frag value at (n=c, k=d) = W[d][c]; element (c, d=2lam+{0,1}) packs to
//    u32 idx = (((c>>4)*4 + (lam>>4))*64 + ((lam>>2)&3)*16 + (c&15))*4 + (lam&3)
// ---------------------------------------------------------------------------
__global__ void __launch_bounds__(64)
build_w_kernel(const float2* __restrict__ csn, __bf16* __restrict__ wtf)
{
    const int mat = blockIdx.x >> 5;
    const int grp = blockIdx.x & 31;
    const int c0  = grp * 4;
    const int lam = threadIdx.x;

    const float2* base = csn + (mat * 256) * 64 + lam;

    float vlo[4], vhi[4];
#pragma unroll
    for (int j = 0; j < 4; j++) {
        vlo[j] = (2 * lam     == c0 + j) ? 1.f : 0.f;
        vhi[j] = (2 * lam + 1 == c0 + j) ? 1.f : 0.f;
    }

    float2 buf[3][16];
#pragma unroll
    for (int k = 0; k < 16; k++) buf[0][k] = base[k * 64];
#pragma unroll
    for (int k = 0; k < 16; k++) buf[1][k] = base[(16 + k) * 64];

#pragma unroll
    for (int g = 0; g < 16; g++) {
        const int cb = g % 3;
        if (g < 14) {
            const int nb = (g + 2) % 3;
#pragma unroll
            for (int k = 0; k < 16; k++)
                buf[nb][k] = base[((g + 2) * 16 + k) * 64];
        }
#pragma unroll
        for (int p = 0; p < 8; p++) {
            {
                const float cs = buf[cb][2 * p].x, sn = buf[cb][2 * p].y;
#pragma unroll
                for (int j = 0; j < 4; j++) {
                    float lo = vlo[j], hi = vhi[j];
                    vlo[j] = cs * lo - sn * hi;
                    vhi[j] = sn * lo + cs * hi;
                }
            }
            {
                const float cs = buf[cb][2 * p + 1].x, sn = buf[cb][2 * p + 1].y;
#pragma unroll
                for (int j = 0; j < 4; j++) {
                    float y  = __shfl_down(vlo[j], 1);
                    float x  = vhi[j];
                    float xn = cs * x - sn * y;
                    float yn = sn * x + cs * y;
                    vhi[j] = xn;
                    float z = __shfl_up(yn, 1);
                    if (lam > 0) vlo[j] = z;
                }
            }
        }
    }

    u32* wtu = (u32*)wtf;
#pragma unroll
    for (int j = 0; j < 4; j++) {
        const int c = c0 + j;
        __bf16 va = (__bf16)vlo[j];
        __bf16 vb = (__bf16)vhi[j];
        u32 pk = (u32)__builtin_bit_cast(unsigned short, va)
               | ((u32)__builtin_bit_cast(unsigned short, vb) << 16);
        const int idx = (((c >> 4) * 4 + (lam >> 4)) * 64
                         + ((lam >> 2) & 3) * 16 + (c & 15)) * 4 + (lam & 3);
        wtu[mat * 8192 + idx] = pk;
    }
}

// ---------------------------------------------------------------------------
// 2) embed: 512 thr = 4 tokens/block (ew read once per block via L1).
//    LN0 -> hf (f32), hb (bf16), invn = rsqrt(Sum h^2).
// ---------------------------------------------------------------------------
__global__ void __launch_bounds__(512)
embed_kernel(const float* __restrict__ x,  const float* __restrict__ ew,
             const float* __restrict__ eb, const float* __restrict__ ct,
             const float* __restrict__ g0, const float* __restrict__ b0,
             float* __restrict__ hf, __bf16* __restrict__ hb,
             float* __restrict__ invn)
{
    __shared__ float sx[4][48];
    __shared__ float sred[4][2];
    const int d  = threadIdx.x & 127, sq = threadIdx.x >> 7;
    const int wh = (threadIdx.x >> 6) & 1;
    const int b  = blockIdx.x & 127;
    const int s  = (blockIdx.x >> 7) * 4 + sq;

    if (s > 0 && d < 48) sx[sq][d] = x[(b * 127 + (s - 1)) * 48 + d];
    __syncthreads();

    float val;
    if (s == 0) {
        val = ct[d];
    } else {
        float aa = 0.f;
#pragma unroll
        for (int f = 0; f < 48; f++) aa = fmaf(sx[sq][f], ew[d * 48 + f], aa);
        val = aa + eb[d];
    }
    float v = val;
#pragma unroll
    for (int m = 32; m; m >>= 1) v += __shfl_xor(v, m);
    if ((threadIdx.x & 63) == 0) sred[sq][wh] = v;
    __syncthreads();
    float mean = (sred[sq][0] + sred[sq][1]) * (1.f / 128.f);
    float xc   = val - mean;
    __syncthreads();
    v = xc * xc;
#pragma unroll
    for (int m = 32; m; m >>= 1) v += __shfl_xor(v, m);
    if ((threadIdx.x & 63) == 0) sred[sq][wh] = v;
    __syncthreads();
    float var = (sred[sq][0] + sred[sq][1]) * (1.f / 128.f);
    float y   = xc * rsqrtf(var + 1e-5f) * g0[d] + b0[d];
    __syncthreads();
    v = y * y;
#pragma unroll
    for (int m = 32; m; m >>= 1) v += __shfl_xor(v, m);
    if ((threadIdx.x & 63) == 0) sred[sq][wh] = v;
    __syncthreads();
    float ss = sred[sq][0] + sred[sq][1];

    const int o = (b * 128 + s) * 128 + d;
    hf[o] = y;
    hb[o] = (__bf16)y;
    if (d == 0) invn[b * 128 + s] = rsqrtf(ss);
}

// ---------------------------------------------------------------------------
// 3) fused attention head: one WG per (head, batch). 512 thr = 8 waves,
//    wave w owns rows w*16..w*16+15. LDS: sH (h -> V^T) + sY (T1 -> Pm).
//    BOTH weight B-operands (wtf, vwf) are global frag-major (L1/L2-hot).
//    A: T1 = h @ W (B glob) | B: G = T1 @ h^T, softmax -> Pm
//    C: V = h @ Vw^T (B glob) | D: O = Pm @ V, +h, LN, *mw -> hs
//    Barriers: B1 (staging), B4 (sH reads done), B5 (V^T visible).
// ---------------------------------------------------------------------------
__global__ void __launch_bounds__(512, 4)
attn_kernel(int l,
            const float*  __restrict__ hf,  const __bf16* __restrict__ hb,
            const float*  __restrict__ invn, const __bf16* __restrict__ wtf,
            const __bf16* __restrict__ vwf, const float* __restrict__ vb,
            const float* __restrict__ lng,  const float* __restrict__ lnb,
            const float* __restrict__ mwp,  __bf16* __restrict__ hs)
{
    __shared__ __align__(16) __bf16 sH[128 * 128];
    __shared__ __align__(16) __bf16 sY[128 * 128];
    __shared__ float sInv[128];
    __shared__ float sVb[128];
    __shared__ float sLg[128];
    __shared__ float sLb[128];

    const int tid  = threadIdx.x;
    const int lane = tid & 63, w = tid >> 6;
    const int l15  = lane & 15, quad = lane >> 4;
    const int b    = blockIdx.x & 127;   // XCD = b%8
    const int hh   = blockIdx.x >> 7;
    const int lh   = l * 8 + hh;

    const __bf16* hbp = hb + b * 16384;

    // ---- stage sH (h), swizzled; scalars ----
#pragma unroll
    for (int c = 0; c < 4; c++) {
        int ch  = tid + c * 512;          // 2048 chunks of 8 bf16
        int row = ch >> 4, cc = ch & 15;
        bf16x8 hv = *(const bf16x8*)(hbp + ch * 8);
        *(bf16x8*)(&sH[sidx(row, cc * 8)]) = hv;
    }
    if (tid < 128) {
        sInv[tid] = invn[b * 128 + tid];
        sVb[tid]  = vb[lh * 128 + tid];
        sLg[tid]  = lng[lh * 128 + tid];
        sLb[tid]  = lnb[lh * 128 + tid];
    }
    __syncthreads();  // B1

    const int r0 = w * 16;
    const int kq = quad * 8;
    const int q4 = quad * 4;
    const f32x4 vzero = {0.f, 0.f, 0.f, 0.f};

    f32x4 acc[8];

    // A-op from sH rows r0.., B-op from global frag-major base
    auto mmG = [&](const __bf16* gbase) {
#pragma unroll
        for (int t = 0; t < 8; t++) acc[t] = vzero;
        const __bf16* gp = gbase + lane * 8;
#pragma unroll
        for (int k0c = 0; k0c < 4; k0c++) {
            bf16x8 a0 = *(const bf16x8*)(&sH[sidx(r0 + l15, k0c * 32 + kq)]);
#pragma unroll
            for (int t = 0; t < 8; t++) {
                bf16x8 bb = *(const bf16x8*)(gp + (t * 4 + k0c) * 512);
                acc[t] = __builtin_amdgcn_mfma_f32_16x16x32_bf16(a0, bb, acc[t], 0, 0, 0);
            }
        }
    };
    // A-op from sY rows r0.. (wave-private), B-op from sH (all rows)
    auto mmL = [&]() {
#pragma unroll
        for (int t = 0; t < 8; t++) acc[t] = vzero;
#pragma unroll
        for (int k0 = 0; k0 < 128; k0 += 32) {
            const int kk = k0 + kq;
            bf16x8 a0 = *(const bf16x8*)(&sY[sidx(r0 + l15, kk)]);
#pragma unroll
            for (int t = 0; t < 8; t++) {
                bf16x8 bb = *(const bf16x8*)(&sH[sidx(t * 16 + l15, kk)]);
                acc[t] = __builtin_amdgcn_mfma_f32_16x16x32_bf16(a0, bb, acc[t], 0, 0, 0);
            }
        }
    };

    // ================= Phase A: T1 = h @ W (B from global wtf) ============
    mmG(wtf + (size_t)lh * 16384);
#pragma unroll
    for (int t = 0; t < 8; t++)
#pragma unroll
        for (int r = 0; r < 4; r++)
            sY[sidx(r0 + q4 + r, t * 16 + l15)] = (__bf16)acc[t][r];
    // no barrier: phase B reads only this wave's own T1 rows

    // ================= Phase B: G = T1 @ h^T =================
    mmL();

    // ---- softmax (base 2): v = G^2*inv_s*inv_t*(scale*log2e) -> Pm in sY ---
    {
        const float scale2 = 0.08838834764831843f * 1.4426950408889634f;
        float invt[8];
#pragma unroll
        for (int t = 0; t < 8; t++) invt[t] = sInv[t * 16 + l15];
        float invs[4];
#pragma unroll
        for (int r = 0; r < 4; r++) invs[r] = sInv[r0 + q4 + r];

        float mx[4] = {-3e38f, -3e38f, -3e38f, -3e38f};
#pragma unroll
        for (int t = 0; t < 8; t++)
#pragma unroll
            for (int r = 0; r < 4; r++) {
                float g = acc[t][r];
                float v = g * g * invs[r] * invt[t] * scale2;
                acc[t][r] = v;
                mx[r] = fmaxf(mx[r], v);
            }
#pragma unroll
        for (int m = 1; m < 16; m <<= 1)
#pragma unroll
            for (int r = 0; r < 4; r++) mx[r] = fmaxf(mx[r], __shfl_xor(mx[r], m));

        float sm[4] = {0.f, 0.f, 0.f, 0.f};
#pragma unroll
        for (int t = 0; t < 8; t++)
#pragma unroll
            for (int r = 0; r < 4; r++) {
                float e = exp2f(acc[t][r] - mx[r]);
                acc[t][r] = e;
                sm[r] += e;
            }
#pragma unroll
        for (int m = 1; m < 16; m <<= 1)
#pragma unroll
            for (int r = 0; r < 4; r++) sm[r] += __shfl_xor(sm[r], m);
#pragma unroll
        for (int r = 0; r < 4; r++) sm[r] = 1.0f / sm[r];
#pragma unroll
        for (int t = 0; t < 8; t++)
#pragma unroll
            for (int r = 0; r < 4; r++)
                sY[sidx(r0 + q4 + r, t * 16 + l15)] = (__bf16)(acc[t][r] * sm[r]);
    }

    // residual prefetch (consumed in epilogue)
    float hres[8][4];
    {
        const float* hfp = hf + (b * 128 + r0 + q4) * 128;
#pragma unroll
        for (int t = 0; t < 8; t++)
#pragma unroll
            for (int r = 0; r < 4; r++)
                hres[t][r] = hfp[r * 128 + t * 16 + l15];
    }

    // ================= Phase C: V = h @ Vw^T (B from global vwf) ==========
    mmG(vwf + (size_t)lh * 16384);
    __syncthreads();  // B4: all waves done reading sH (phases B & C)

    {   // V^T into sH: sH[e][token]
        float vbv[8];
#pragma unroll
        for (int t = 0; t < 8; t++) vbv[t] = sVb[t * 16 + l15];
#pragma unroll
        for (int t = 0; t < 8; t++)
#pragma unroll
            for (int r = 0; r < 4; r++)
                sH[sidx(t * 16 + l15, r0 + q4 + r)] = (__bf16)(acc[t][r] + vbv[t]);
    }
    __syncthreads();  // B5

    // ================= Phase D: O = Pm @ V =================
    mmL();

    {   // epilogue: +h, LN over d, *merger_w -> hs
        const float mw = mwp[lh];
        float lgv[8], lbv[8];
#pragma unroll
        for (int t = 0; t < 8; t++) {
            lgv[t] = sLg[t * 16 + l15];
            lbv[t] = sLb[t * 16 + l15];
        }
        float sum_[4] = {0.f, 0.f, 0.f, 0.f};
        float sq_[4]  = {0.f, 0.f, 0.f, 0.f};
#pragma unroll
        for (int t = 0; t < 8; t++)
#pragma unroll
            for (int r = 0; r < 4; r++) {
                float xx = acc[t][r] + hres[t][r];
                acc[t][r] = xx;
                sum_[r] += xx;
                sq_[r]  += xx * xx;
            }
#pragma unroll
        for (int m = 1; m < 16; m <<= 1)
#pragma unroll
            for (int r = 0; r < 4; r++) {
                sum_[r] += __shfl_xor(sum_[r], m);
                sq_[r]  += __shfl_xor(sq_[r], m);
            }
        float mean[4], rstd[4];
#pragma unroll
        for (int r = 0; r < 4; r++) {
            mean[r] = sum_[r] * (1.f / 128.f);
            float var = sq_[r] * (1.f / 128.f) - mean[r] * mean[r];
            rstd[r] = rsqrtf(fmaxf(var, 0.f) + 1e-5f);
        }
        __bf16* hsp = hs + ((hh * 128 + b) * 128 + r0 + q4) * 128;
#pragma unroll
        for (int t = 0; t < 8; t++)
#pragma unroll
            for (int r = 0; r < 4; r++) {
                float y = (acc[t][r] - mean[r]) * rstd[r] * lgv[t] + lbv[t];
                hsp[r * 128 + t * 16 + l15] = (__bf16)(y * mw);
            }
    }
}

// ---------------------------------------------------------------------------
static __device__ __forceinline__ float block_sum_128(float v, float* sred)
{
#pragma unroll
    for (int m = 32; m; m >>= 1) v += __shfl_xor(v, m);
    __syncthreads();
    if ((threadIdx.x & 63) == 0) sred[threadIdx.x >> 6] = v;
    __syncthreads();
    return sred[0] + sred[1];
}

// ---------------------------------------------------------------------------
// 4) merge heads + prep next layer. Last layer writes f32 out = h[:,127,:].
// ---------------------------------------------------------------------------
__global__ void __launch_bounds__(128)
merge_kernel(const __bf16* __restrict__ hs, const float* __restrict__ mbp, int l,
             float* __restrict__ hf, __bf16* __restrict__ hb, float* __restrict__ invn,
             float* __restrict__ out, int last)
{
    __shared__ float sred[2];
    const int b = blockIdx.x & 127, s = blockIdx.x >> 7, d = threadIdx.x;

    float acc = mbp[l];
#pragma unroll
    for (int h = 0; h < 8; h++)
        acc += (float)hs[((h * 128 + b) * 128 + s) * 128 + d];

    float ss = block_sum_128(acc * acc, sred);

    const int o = (b * 128 + s) * 128 + d;
    hf[o] = acc;
    hb[o] = (__bf16)acc;
    if (d == 0) invn[b * 128 + s] = rsqrtf(ss);
    if (last && s == 127) out[b * 128 + d] = acc;
}

// ---------------------------------------------------------------------------
extern "C" void kernel_launch(void* const* d_in, const int* in_sizes, int n_in,
                              void* d_out, int out_size, void* d_ws, size_t ws_size,
                              hipStream_t stream)
{
    (void)in_sizes; (void)n_in; (void)out_size; (void)ws_size;

    const float* x   = (const float*)d_in[0];
    const float* ew  = (const float*)d_in[1];
    const float* eb  = (const float*)d_in[2];
    const float* ct  = (const float*)d_in[3];
    const float* g0  = (const float*)d_in[4];
    const float* b0  = (const float*)d_in[5];
    const float* vw  = (const float*)d_in[6];
    const float* vb  = (const float*)d_in[7];
    const float* lng = (const float*)d_in[8];
    const float* lnb = (const float*)d_in[9];
    const float* phi = (const float*)d_in[10];
    const float* mw  = (const float*)d_in[11];
    const float* mb  = (const float*)d_in[12];
    float* out = (float*)d_out;

    char* ws = (char*)d_ws;
    __bf16* wtf  = (__bf16*)(ws);                 //  1,572,864 (frag-major Wt)
    float*  hf   = (float*)(ws + 1572864);        //  8,388,608
    __bf16* hb   = (__bf16*)(ws + 9961472);       //  4,194,304
    float*  invn = (float*)(ws + 14155776);       //     65,536
    __bf16* hs   = (__bf16*)(ws + 14221312);      // 33,554,432
    __bf16* cvwf = (__bf16*)(ws + 47775744);      //  1,572,864 (frag-major Vw)
    float2* csn  = (float2*)(ws + 49348608);      //  6,291,456  (~55.6 MB)

    prep_kernel<<<3456, 256, 0, stream>>>(phi, csn, vw, cvwf);
    build_w_kernel<<<1536, 64, 0, stream>>>(csn, wtf);
    embed_kernel<<<4096, 512, 0, stream>>>(x, ew, eb, ct, g0, b0, hf, hb, invn);
    for (int l = 0; l < 6; l++) {
        attn_kernel<<<1024, 512, 0, stream>>>(l, hf, hb, invn, wtf, cvwf, vb,
                                              lng, lnb, mw, hs);
        merge_kernel<<<16384, 128, 0, stream>>>(hs, mb, l, hf, hb, invn, out,
                                                (l == 5) ? 1 : 0);
    }
}

// Round 12
// 422.001 us; speedup vs baseline: 1.6805x; 1.0980x over previous
//
#include <hip/hip_runtime.h>
#include <hip/hip_bf16.h>

// ---------------------------------------------------------------------------
// Quantum ViT: B=128, T=127, D_IN=48, DK=S=128, H=8, L=6, P=8128
// Inputs: all float32. Output: float32 [B, DK]. bf16 MFMA internals.
//
// R12: R8 baseline (best: 427us) + wave-per-token merge (256thr/4 tokens,
// packed u32 loads, in-wave 64-lane reduction, no LDS/barriers). R9's inline
// merge (420MB extra traffic) and R11's cooperative mega-kernel (launch never
// executed) are both abandoned per counters. attn kept at its measured
// plateau config (~47us: 8 waves x 16 rows, XOR swizzle, 2 LDS buffers,
// frag-major Vw from global, b-major grid).
// ---------------------------------------------------------------------------

typedef __bf16 bf16x8 __attribute__((ext_vector_type(8)));
typedef float  f32x4  __attribute__((ext_vector_type(4)));
typedef unsigned int u32;

// swizzled LDS index for a 128x128 bf16 tile: chunk(col/8) ^= row&15.
__device__ __forceinline__ int sidx(int row, int col)
{
    return row * 128 + ((((col >> 3) ^ (row & 15)) << 3) | (col & 7));
}

// ---------------------------------------------------------------------------
// 0) prep: [0..3071] sincos table (layer-major, 256 layers, pad=identity)
//          [3072..3455] Vw f32 -> bf16 fragment-major
// ---------------------------------------------------------------------------
__global__ void __launch_bounds__(256)
prep_kernel(const float* __restrict__ phi, float2* __restrict__ csn,
            const float* __restrict__ vw,  __bf16* __restrict__ cvwf)
{
    if (blockIdx.x < 3072) {
        const int mat = blockIdx.x >> 6;
        const int t   = ((blockIdx.x & 63) << 2) + (threadIdx.x >> 6);
        const int j   = threadIdx.x & 63;
        float th = 0.f;
        if (t < 253) {
            const int p = t & 1, i = 2 * j + p;
            const int lim = min(t, 252 - t);
            if (i <= lim) {
                const int k = (t + i) >> 1;
                th = phi[mat * 8128 + ((k * (k + 1)) >> 1) + (k - i)];
            }
        }
        float sn, cs;
        __sincosf(th, &sn, &cs);
        csn[(mat * 256 + t) * 64 + j] = make_float2(cs, sn);
    } else {
        const int f    = (blockIdx.x - 3072) * 256 + threadIdx.x;  // 98304 frags
        const int lane = f & 63;
        const int k0   = (f >> 6) & 3;
        const int t    = (f >> 8) & 7;
        const int lh   = f >> 11;
        const int row  = t * 16 + (lane & 15);
        const int col  = k0 * 32 + (lane >> 4) * 8;
        const float* src = vw + (lh * 128 + row) * 128 + col;
        __bf16* dst = cvwf + f * 8;
#pragma unroll
        for (int j2 = 0; j2 < 8; j2++) dst[j2] = (__bf16)src[j2];
    }
}

// ---------------------------------------------------------------------------
// 1) W build: 253 parallel Givens layers (time(k,i)=2k-i), 16-layer groups,
//    3-slot register buffer, prefetch 2 groups ahead. 4 cols/block.
//    Output Wt[mat][c][d] = W[d][c] (bf16, B-operand layout).
// ---------------------------------------------------------------------------
__global__ void __launch_bounds__(64)
build_w_kernel(const float2* __restrict__ csn, __bf16* __restrict__ wt)
{
    const int mat = blockIdx.x >> 5;
    const int grp = blockIdx.x & 31;
    const int c0  = grp * 4;
    const int lam = threadIdx.x;

    const float2* base = csn + (mat * 256) * 64 + lam;

    float vlo[4], vhi[4];
#pragma unroll
    for (int j = 0; j < 4; j++) {
        vlo[j] = (2 * lam     == c0 + j) ? 1.f : 0.f;
        vhi[j] = (2 * lam + 1 == c0 + j) ? 1.f : 0.f;
    }

    float2 buf[3][16];
#pragma unroll
    for (int k = 0; k < 16; k++) buf[0][k] = base[k * 64];
#pragma unroll
    for (int k = 0; k < 16; k++) buf[1][k] = base[(16 + k) * 64];

#pragma unroll
    for (int g = 0; g < 16; g++) {
        const int cb = g % 3;
        if (g < 14) {
            const int nb = (g + 2) % 3;
#pragma unroll
            for (int k = 0; k < 16; k++)
                buf[nb][k] = base[((g + 2) * 16 + k) * 64];
        }
#pragma unroll
        for (int p = 0; p < 8; p++) {
            {
                const float cs = buf[cb][2 * p].x, sn = buf[cb][2 * p].y;
#pragma unroll
                for (int j = 0; j < 4; j++) {
                    float lo = vlo[j], hi = vhi[j];
                    vlo[j] = cs * lo - sn * hi;
                    vhi[j] = sn * lo + cs * hi;
                }
            }
            {
                const float cs = buf[cb][2 * p + 1].x, sn = buf[cb][2 * p + 1].y;
#pragma unroll
                for (int j = 0; j < 4; j++) {
                    float y  = __shfl_down(vlo[j], 1);
                    float x  = vhi[j];
                    float xn = cs * x - sn * y;
                    float yn = sn * x + cs * y;
                    vhi[j] = xn;
                    float z = __shfl_up(yn, 1);
                    if (lam > 0) vlo[j] = z;
                }
            }
        }
    }

    u32* wtu = (u32*)wt;
#pragma unroll
    for (int j = 0; j < 4; j++) {
        __bf16 va = (__bf16)vlo[j];
        __bf16 vb = (__bf16)vhi[j];
        u32 pk = (u32)__builtin_bit_cast(unsigned short, va)
               | ((u32)__builtin_bit_cast(unsigned short, vb) << 16);
        wtu[mat * 8192 + (c0 + j) * 64 + lam] = pk;
    }
}

// ---------------------------------------------------------------------------
// 2) embed: 512 thr = 4 tokens/block (ew read once per block via L1).
//    LN0 -> hf (f32), hb (bf16), invn = rsqrt(Sum h^2).
// ---------------------------------------------------------------------------
__global__ void __launch_bounds__(512)
embed_kernel(const float* __restrict__ x,  const float* __restrict__ ew,
             const float* __restrict__ eb, const float* __restrict__ ct,
             const float* __restrict__ g0, const float* __restrict__ b0,
             float* __restrict__ hf, __bf16* __restrict__ hb,
             float* __restrict__ invn)
{
    __shared__ float sx[4][48];
    __shared__ float sred[4][2];
    const int d  = threadIdx.x & 127, sq = threadIdx.x >> 7;
    const int wh = (threadIdx.x >> 6) & 1;
    const int b  = blockIdx.x & 127;
    const int s  = (blockIdx.x >> 7) * 4 + sq;

    if (s > 0 && d < 48) sx[sq][d] = x[(b * 127 + (s - 1)) * 48 + d];
    __syncthreads();

    float val;
    if (s == 0) {
        val = ct[d];
    } else {
        float aa = 0.f;
#pragma unroll
        for (int f = 0; f < 48; f++) aa = fmaf(sx[sq][f], ew[d * 48 + f], aa);
        val = aa + eb[d];
    }
    float v = val;
#pragma unroll
    for (int m = 32; m; m >>= 1) v += __shfl_xor(v, m);
    if ((threadIdx.x & 63) == 0) sred[sq][wh] = v;
    __syncthreads();
    float mean = (sred[sq][0] + sred[sq][1]) * (1.f / 128.f);
    float xc   = val - mean;
    __syncthreads();
    v = xc * xc;
#pragma unroll
    for (int m = 32; m; m >>= 1) v += __shfl_xor(v, m);
    if ((threadIdx.x & 63) == 0) sred[sq][wh] = v;
    __syncthreads();
    float var = (sred[sq][0] + sred[sq][1]) * (1.f / 128.f);
    float y   = xc * rsqrtf(var + 1e-5f) * g0[d] + b0[d];
    __syncthreads();
    v = y * y;
#pragma unroll
    for (int m = 32; m; m >>= 1) v += __shfl_xor(v, m);
    if ((threadIdx.x & 63) == 0) sred[sq][wh] = v;
    __syncthreads();
    float ss = sred[sq][0] + sred[sq][1];

    const int o = (b * 128 + s) * 128 + d;
    hf[o] = y;
    hb[o] = (__bf16)y;
    if (d == 0) invn[b * 128 + s] = rsqrtf(ss);
}

// ---------------------------------------------------------------------------
// 3) fused attention head (R8 exact body): one WG per (head, batch).
//    512 thr = 8 waves, wave w owns rows w*16..w*16+15.
//    LDS: sH (h -> V^T) + sY (Wt -> T1 -> Pm). Vw B-frags from global.
//    A: T1 = h @ W        | B: G = T1 @ h^T, softmax -> Pm
//    C: V = h @ Vw^T      | D: O = Pm @ V, +h, LN, *mw -> hs
//    scores = G^2 * inv_ns * inv_nt * scale  (softmax in base 2)
// ---------------------------------------------------------------------------
__global__ void __launch_bounds__(512, 4)
attn_kernel(int l,
            const float*  __restrict__ hf,  const __bf16* __restrict__ hb,
            const float*  __restrict__ invn, const __bf16* __restrict__ wt,
            const __bf16* __restrict__ vwf, const float* __restrict__ vb,
            const float* __restrict__ lng,  const float* __restrict__ lnb,
            const float* __restrict__ mwp,  __bf16* __restrict__ hs)
{
    __shared__ __align__(16) __bf16 sH[128 * 128];
    __shared__ __align__(16) __bf16 sY[128 * 128];
    __shared__ float sInv[128];
    __shared__ float sVb[128];
    __shared__ float sLg[128];
    __shared__ float sLb[128];

    const int tid  = threadIdx.x;
    const int lane = tid & 63, w = tid >> 6;
    const int l15  = lane & 15, quad = lane >> 4;
    const int b    = blockIdx.x & 127;   // XCD = b%8
    const int hh   = blockIdx.x >> 7;
    const int lh   = l * 8 + hh;

    const __bf16* hbp = hb + b * 16384;
    const __bf16* wtp = wt + lh * 16384;

    // ---- stage sH (h) + sY (Wt), swizzled ----
#pragma unroll
    for (int c = 0; c < 4; c++) {
        int ch  = tid + c * 512;          // 2048 chunks of 8 bf16
        int row = ch >> 4, cc = ch & 15;
        bf16x8 hv = *(const bf16x8*)(hbp + ch * 8);
        bf16x8 wv = *(const bf16x8*)(wtp + ch * 8);
        *(bf16x8*)(&sH[sidx(row, cc * 8)]) = hv;
        *(bf16x8*)(&sY[sidx(row, cc * 8)]) = wv;
    }
    if (tid < 128) {
        sInv[tid] = invn[b * 128 + tid];
        sVb[tid]  = vb[lh * 128 + tid];
        sLg[tid]  = lng[lh * 128 + tid];
        sLb[tid]  = lnb[lh * 128 + tid];
    }
    __syncthreads();  // B1

    const int r0 = w * 16;
    const int kq = quad * 8;
    const int q4 = quad * 4;
    const f32x4 vzero = {0.f, 0.f, 0.f, 0.f};

    f32x4 acc[8];

    auto mmL = [&](const __bf16* Ab, const __bf16* Bb) {
#pragma unroll
        for (int t = 0; t < 8; t++) acc[t] = vzero;
#pragma unroll
        for (int k0 = 0; k0 < 128; k0 += 32) {
            const int kk = k0 + kq;
            bf16x8 a0 = *(const bf16x8*)(&Ab[sidx(r0 + l15, kk)]);
#pragma unroll
            for (int t = 0; t < 8; t++) {
                bf16x8 bb = *(const bf16x8*)(&Bb[sidx(t * 16 + l15, kk)]);
                acc[t] = __builtin_amdgcn_mfma_f32_16x16x32_bf16(a0, bb, acc[t], 0, 0, 0);
            }
        }
    };

    // ================= Phase A: T1 = h @ W =================
    mmL(sH, sY);
    __syncthreads();  // B2: all waves done reading sY(Wt)
#pragma unroll
    for (int t = 0; t < 8; t++)
#pragma unroll
        for (int r = 0; r < 4; r++)
            sY[sidx(r0 + q4 + r, t * 16 + l15)] = (__bf16)acc[t][r];
    // no barrier: phase B reads only this wave's own T1 rows

    // ================= Phase B: G = T1 @ h^T =================
    mmL(sY, sH);

    // ---- softmax (base 2): v = G^2*inv_s*inv_t*(scale*log2e) -> Pm in sY ---
    {
        const float scale2 = 0.08838834764831843f * 1.4426950408889634f;
        float invt[8];
#pragma unroll
        for (int t = 0; t < 8; t++) invt[t] = sInv[t * 16 + l15];
        float invs[4];
#pragma unroll
        for (int r = 0; r < 4; r++) invs[r] = sInv[r0 + q4 + r];

        float mx[4] = {-3e38f, -3e38f, -3e38f, -3e38f};
#pragma unroll
        for (int t = 0; t < 8; t++)
#pragma unroll
            for (int r = 0; r < 4; r++) {
                float g = acc[t][r];
                float v = g * g * invs[r] * invt[t] * scale2;
                acc[t][r] = v;
                mx[r] = fmaxf(mx[r], v);
            }
#pragma unroll
        for (int m = 1; m < 16; m <<= 1)
#pragma unroll
            for (int r = 0; r < 4; r++) mx[r] = fmaxf(mx[r], __shfl_xor(mx[r], m));

        float sm[4] = {0.f, 0.f, 0.f, 0.f};
#pragma unroll
        for (int t = 0; t < 8; t++)
#pragma unroll
            for (int r = 0; r < 4; r++) {
                float e = exp2f(acc[t][r] - mx[r]);
                acc[t][r] = e;
                sm[r] += e;
            }
#pragma unroll
        for (int m = 1; m < 16; m <<= 1)
#pragma unroll
            for (int r = 0; r < 4; r++) sm[r] += __shfl_xor(sm[r], m);
#pragma unroll
        for (int r = 0; r < 4; r++) sm[r] = 1.0f / sm[r];
#pragma unroll
        for (int t = 0; t < 8; t++)
#pragma unroll
            for (int r = 0; r < 4; r++)
                sY[sidx(r0 + q4 + r, t * 16 + l15)] = (__bf16)(acc[t][r] * sm[r]);
    }

    // residual prefetch (consumed in epilogue)
    float hres[8][4];
    {
        const float* hfp = hf + (b * 128 + r0 + q4) * 128;
#pragma unroll
        for (int t = 0; t < 8; t++)
#pragma unroll
            for (int r = 0; r < 4; r++)
                hres[t][r] = hfp[r * 128 + t * 16 + l15];
    }

    // ================= Phase C: V = h @ Vw^T (B-frags from global) ========
    {
        const __bf16* vbase = vwf + (size_t)lh * 16384;
#pragma unroll
        for (int t = 0; t < 8; t++) acc[t] = vzero;
#pragma unroll
        for (int k0c = 0; k0c < 4; k0c++) {
            const int kk = k0c * 32 + kq;
            bf16x8 a0 = *(const bf16x8*)(&sH[sidx(r0 + l15, kk)]);
#pragma unroll
            for (int t = 0; t < 8; t++) {
                bf16x8 bb = *(const bf16x8*)(vbase + ((t * 4 + k0c) * 64 + lane) * 8);
                acc[t] = __builtin_amdgcn_mfma_f32_16x16x32_bf16(a0, bb, acc[t], 0, 0, 0);
            }
        }
    }
    __syncthreads();  // B4: all waves done reading sH (phases B & C)

    {   // V^T into sH: sH[e][token]
        float vbv[8];
#pragma unroll
        for (int t = 0; t < 8; t++) vbv[t] = sVb[t * 16 + l15];
#pragma unroll
        for (int t = 0; t < 8; t++)
#pragma unroll
            for (int r = 0; r < 4; r++)
                sH[sidx(t * 16 + l15, r0 + q4 + r)] = (__bf16)(acc[t][r] + vbv[t]);
    }
    __syncthreads();  // B5

    // ================= Phase D: O = Pm @ V =================
    mmL(sY, sH);

    {   // epilogue: +h, LN over d, *merger_w -> hs
        const float mw = mwp[lh];
        float lgv[8], lbv[8];
#pragma unroll
        for (int t = 0; t < 8; t++) {
            lgv[t] = sLg[t * 16 + l15];
            lbv[t] = sLb[t * 16 + l15];
        }
        float sum_[4] = {0.f, 0.f, 0.f, 0.f};
        float sq_[4]  = {0.f, 0.f, 0.f, 0.f};
#pragma unroll
        for (int t = 0; t < 8; t++)
#pragma unroll
            for (int r = 0; r < 4; r++) {
                float xx = acc[t][r] + hres[t][r];
                acc[t][r] = xx;
                sum_[r] += xx;
                sq_[r]  += xx * xx;
            }
#pragma unroll
        for (int m = 1; m < 16; m <<= 1)
#pragma unroll
            for (int r = 0; r < 4; r++) {
                sum_[r] += __shfl_xor(sum_[r], m);
                sq_[r]  += __shfl_xor(sq_[r], m);
            }
        float mean[4], rstd[4];
#pragma unroll
        for (int r = 0; r < 4; r++) {
            mean[r] = sum_[r] * (1.f / 128.f);
            float var = sq_[r] * (1.f / 128.f) - mean[r] * mean[r];
            rstd[r] = rsqrtf(fmaxf(var, 0.f) + 1e-5f);
        }
        __bf16* hsp = hs + ((hh * 128 + b) * 128 + r0 + q4) * 128;
#pragma unroll
        for (int t = 0; t < 8; t++)
#pragma unroll
            for (int r = 0; r < 4; r++) {
                float y = (acc[t][r] - mean[r]) * rstd[r] * lgv[t] + lbv[t];
                hsp[r * 128 + t * 16 + l15] = (__bf16)(y * mw);
            }
    }
}

// ---------------------------------------------------------------------------
// 4) merge v2: one wave per token. 256 thr = 4 tokens/block, grid 4096.
//    Lane ln owns d = 2ln..2ln+1 (packed u32). Sum over heads in R8's order;
//    Sum h^2 via single 64-lane butterfly (no LDS, no barriers).
//    Last layer writes f32 out = h[:,127,:].
// ---------------------------------------------------------------------------
__global__ void __launch_bounds__(256)
merge_kernel(const __bf16* __restrict__ hs, const float* __restrict__ mbp, int l,
             float* __restrict__ hf, __bf16* __restrict__ hb, float* __restrict__ invn,
             float* __restrict__ out, int last)
{
    const int b  = blockIdx.x & 127;
    const int s  = (blockIdx.x >> 7) * 4 + (threadIdx.x >> 6);
    const int ln = threadIdx.x & 63;
    const int d2 = ln * 2;

    const float mbv = mbp[l];
    float a0 = mbv, a1 = mbv;
#pragma unroll
    for (int h8 = 0; h8 < 8; h8++) {
        const __bf16* p = hs + (((size_t)h8 * 128 + b) * 128 + s) * 128 + d2;
        a0 += (float)p[0];
        a1 += (float)p[1];
    }
    float v = a0 * a0 + a1 * a1;
#pragma unroll
    for (int m = 32; m; m >>= 1) v += __shfl_xor(v, m);   // Sum over all 128 d

    const size_t o = ((size_t)b * 128 + s) * 128 + d2;
    *(float2*)(hf + o) = make_float2(a0, a1);
    __bf16 p0 = (__bf16)a0, p1 = (__bf16)a1;
    ((u32*)hb)[o >> 1] = (u32)__builtin_bit_cast(unsigned short, p0)
                       | ((u32)__builtin_bit_cast(unsigned short, p1) << 16);
    if (ln == 0) invn[b * 128 + s] = rsqrtf(v);
    if (last && s == 127) *(float2*)(out + b * 128 + d2) = make_float2(a0, a1);
}

// ---------------------------------------------------------------------------
extern "C" void kernel_launch(void* const* d_in, const int* in_sizes, int n_in,
                              void* d_out, int out_size, void* d_ws, size_t ws_size,
                              hipStream_t stream)
{
    (void)in_sizes; (void)n_in; (void)out_size; (void)ws_size;

    const float* x   = (const float*)d_in[0];
    const float* ew  = (const float*)d_in[1];
    const float* eb  = (const float*)d_in[2];
    const float* ct  = (const float*)d_in[3];
    const float* g0  = (const float*)d_in[4];
    const float* b0  = (const float*)d_in[5];
    const float* vw  = (const float*)d_in[6];
    const float* vb  = (const float*)d_in[7];
    const float* lng = (const float*)d_in[8];
    const float* lnb = (const float*)d_in[9];
    const float* phi = (const float*)d_in[10];
    const float* mw  = (const float*)d_in[11];
    const float* mb  = (const float*)d_in[12];
    float* out = (float*)d_out;

    char* ws = (char*)d_ws;
    __bf16* wt   = (__bf16*)(ws);                 //  1,572,864
    float*  hf   = (float*)(ws + 1572864);        //  8,388,608
    __bf16* hb   = (__bf16*)(ws + 9961472);       //  4,194,304
    float*  invn = (float*)(ws + 14155776);       //     65,536
    __bf16* hs   = (__bf16*)(ws + 14221312);      // 33,554,432
    __bf16* cvwf = (__bf16*)(ws + 47775744);      //  1,572,864 (frag-major Vw)
    float2* csn  = (float2*)(ws + 49348608);      //  6,291,456  (~55.6 MB)

    prep_kernel<<<3456, 256, 0, stream>>>(phi, csn, vw, cvwf);
    build_w_kernel<<<1536, 64, 0, stream>>>(csn, wt);
    embed_kernel<<<4096, 512, 0, stream>>>(x, ew, eb, ct, g0, b0, hf, hb, invn);
    for (int l = 0; l < 6; l++) {
        attn_kernel<<<1024, 512, 0, stream>>>(l, hf, hb, invn, wt, cvwf, vb,
                                              lng, lnb, mw, hs);
        merge_kernel<<<4096, 256, 0, stream>>>(hs, mb, l, hf, hb, invn, out,
                                               (l == 5) ? 1 : 0);
    }
}